// Round 10
// baseline (199.610 us; speedup 1.0000x reference)
//
#include <hip/hip_runtime.h>

#define B_ 4
#define T_ 4096
#define D_ 1024
#define H_ 8

typedef unsigned short u16;
typedef unsigned int u32;
typedef __attribute__((ext_vector_type(8))) short s16x8;
typedef __attribute__((ext_vector_type(4))) float f32x4;

#define LOG2E 1.4426950408889634f

__device__ __forceinline__ float ex2(float x){
#if __has_builtin(__builtin_amdgcn_exp2f)
  return __builtin_amdgcn_exp2f(x);
#else
  return exp2f(x);
#endif
}
__device__ __forceinline__ float rcpf(float x){
#if __has_builtin(__builtin_amdgcn_rcpf)
  return __builtin_amdgcn_rcpf(x);
#else
  return __fdividef(1.0f, x);
#endif
}
__device__ __forceinline__ u16 f2bf(float f){       // RNE
  union { float f; u32 i; } v; v.f = f;
  u32 i = v.i;
  return (u16)((i + 0x7FFFu + ((i >> 16) & 1u)) >> 16);
}
__device__ __forceinline__ float sigf(float z){     // 1/(1+e^-z)
  return rcpf(1.0f + ex2(-LOG2E * z));
}
__device__ __forceinline__ s16x8 cvt8(float4 a, float4 b){  // fp32x8 -> bf16x8 (trunc)
  s16x8 r;
  r[0] = (short)(__float_as_uint(a.x) >> 16);
  r[1] = (short)(__float_as_uint(a.y) >> 16);
  r[2] = (short)(__float_as_uint(a.z) >> 16);
  r[3] = (short)(__float_as_uint(a.w) >> 16);
  r[4] = (short)(__float_as_uint(b.x) >> 16);
  r[5] = (short)(__float_as_uint(b.y) >> 16);
  r[6] = (short)(__float_as_uint(b.z) >> 16);
  r[7] = (short)(__float_as_uint(b.w) >> 16);
  return r;
}

// ---------------------------------------------------------------- K0
// wt[(mat*8+h)][e][k] = bf16(w_mat[h][k][e])
__global__ __launch_bounds__(256) void k0_transpose(const float* __restrict__ w_in,
                                                    const float* __restrict__ w_a,
                                                    u16* __restrict__ wt){
  __shared__ float ls[128][132];
  const int blk = blockIdx.x;                       // mat*8+h
  const float* src = (blk < 8 ? w_in : w_a) + (size_t)(blk & 7) * 128 * 128;
  u16* dst = wt + (size_t)blk * 128 * 128;
  const int tid = threadIdx.x;
  const int r0 = tid >> 5;          // 0..7
  const int c0 = (tid & 31) * 4;    // 0..124
  #pragma unroll
  for (int it = 0; it < 16; ++it){
    int r = r0 + it * 8;
    *(float4*)(&ls[r][c0]) = *(const float4*)(src + r * 128 + c0);
  }
  __syncthreads();
  #pragma unroll
  for (int it = 0; it < 16; ++it){
    int e = r0 + it * 8;
    ushort4 u;
    u.x = f2bf(ls[c0 + 0][e]);
    u.y = f2bf(ls[c0 + 1][e]);
    u.z = f2bf(ls[c0 + 2][e]);
    u.w = f2bf(ls[c0 + 3][e]);
    *(ushort4*)(dst + e * 128 + c0) = u;
  }
}

// ================================================================ K1P
// Persistent per-chain kernel, R9: 512 threads = 8 waves x 16 rows each
// (R8's 4x32 ran 1 wave/SIMD — fully latency-exposed). Per-tile critical
// path halves (8 MFMA, 4 gate elems, single shfl chain per wave) and
// 2 waves/SIMD co-resident. xv now prefetched one tile ahead (was the only
// unprefetched load on the critical path). Traffic identical to R8
// (FETCH ~33 MB, WRITE ~65.5 MB — best of any structure so far).
// launch_bounds(512,2): VGPR cap 256 >> est ~150 — no clamp/spill.
__global__ __launch_bounds__(512, 2) void k1_persist(
    const float* __restrict__ x, const float* __restrict__ a_param,
    const u16* __restrict__ wt, float* __restrict__ y_out,
    float* __restrict__ hlast)
{
  __shared__ float waveC[2][8][16][2];   // [tile&1][segment][col][A,Y] (2 KB)

  const int b = blockIdx.x;
  const int h = b & 7;
  const int batch = (b >> 3) & 3;
  const int cg = b >> 5;                 // 16-col group within head
  const int tid = threadIdx.x;
  const int w = tid >> 6;                // wave = 16-row segment, 0..7
  const int lane = tid & 63;
  const int q = lane >> 4, l = lane & 15;
  const int col = l;                     // MFMA C col = lane&15
  const int hcol = h * 128 + cg * 16 + col;

  const float asp = 8.0f * log1pf(__expf(a_param[hcol]));

  // ---- W fragments: tile-invariant, in registers.
  s16x8 bI[4], bA[4];
  {
    const u16* wb = wt + (size_t)(h * 128 + cg * 16 + col) * 128 + q * 8;
    #pragma unroll
    for (int kb = 0; kb < 4; ++kb){
      bI[kb] = *(const s16x8*)(wb + kb * 32);
      bA[kb] = *(const s16x8*)(wb + 8 * 128 * 128 + kb * 32);
    }
  }

  // ---- A-fragment pointer: wave's 16 rows (w*16 + l), k-slab of head h
  const float* pA = x + (size_t)(batch * T_ + w * 16 + l) * D_ + h * 128;
  // ---- xv pointer: rows w*16 + q*4 + r, col hcol
  const float* xp = x + (size_t)(batch * T_ + w * 16 + q * 4) * D_ + hcol;

  float4 Aa[4][2], Ab[4][2];
  float xva[4], xvb[4];
  // prologue: tile 0
  #pragma unroll
  for (int kb = 0; kb < 4; ++kb){
    const int ko = kb * 32 + q * 8;
    Aa[kb][0] = *(const float4*)(pA + ko);
    Aa[kb][1] = *(const float4*)(pA + ko + 4);
  }
  #pragma unroll
  for (int r = 0; r < 4; ++r) xva[r] = xp[(size_t)r * D_];
  pA += 128 * D_; xp += 128 * D_;

  float hin = 0.0f;

  auto tile_step = [&](float4 (&CA)[4][2], float4 (&NA)[4][2],
                       float (&cxv)[4], float (&nxv)[4], int tt)
  {
    const int mb = batch * T_ + tt * 128;
    // issue next-tile loads first (hidden under this tile's compute)
    if (tt + 1 < 32){
      #pragma unroll
      for (int kb = 0; kb < 4; ++kb){
        const int ko = kb * 32 + q * 8;
        NA[kb][0] = *(const float4*)(pA + ko);
        NA[kb][1] = *(const float4*)(pA + ko + 4);
      }
      #pragma unroll
      for (int r = 0; r < 4; ++r) nxv[r] = xp[(size_t)r * D_];
      pA += 128 * D_; xp += 128 * D_;
    }
    // GEMM: 8 MFMA on current buffer
    f32x4 accX = (f32x4)0.0f, accG = (f32x4)0.0f;
    #pragma unroll
    for (int kb = 0; kb < 4; ++kb){
      s16x8 a0 = cvt8(CA[kb][0], CA[kb][1]);
      accX = __builtin_amdgcn_mfma_f32_16x16x32_bf16(a0, bI[kb], accX, 0, 0, 0);
      accG = __builtin_amdgcn_mfma_f32_16x16x32_bf16(a0, bA[kb], accG, 0, 0, 0);
    }
    // gates -> (a,b), 4 elements
    float av[4], bv[4];
    #pragma unroll
    for (int r = 0; r < 4; ++r){
      float gx = sigf(accX[r]);
      float ga = sigf(accG[r]);
      float la = -asp * ga;
      float a  = ex2(LOG2E * la);
      float mult = sqrtf(fmaxf(1.0f - a * a, 0.0f));
      av[r] = a;
      bv[r] = mult * gx * cxv[r];
    }
    // thread-local 4-row combine
    float TA = (av[0] * av[1]) * (av[2] * av[3]);
    float TY = fmaf(av[3], fmaf(av[2], fmaf(av[1], bv[0], bv[1]), bv[2]), bv[3]);
    // q-group scan across the wave's 16 rows
    float QA0 = __shfl(TA, l,      64), QY0 = __shfl(TY, l,      64);
    float QA1 = __shfl(TA, l + 16, 64), QY1 = __shfl(TY, l + 16, 64);
    float QA2 = __shfl(TA, l + 32, 64), QY2 = __shfl(TY, l + 32, 64);
    float QA3 = __shfl(TA, l + 48, 64), QY3 = __shfl(TY, l + 48, 64);
    float P1A = QA0,       P1Y = QY0;
    float P2A = P1A * QA1, P2Y = fmaf(QA1, P1Y, QY1);
    float P3A = P2A * QA2, P3Y = fmaf(QA2, P2Y, QY2);
    float QpA = (q == 0) ? 1.0f : ((q == 1) ? P1A : ((q == 2) ? P2A : P3A));
    float QpY = (q == 0) ? 0.0f : ((q == 1) ? P1Y : ((q == 2) ? P2Y : P3Y));
    float SA = P3A * QA3, SY = fmaf(QA3, P3Y, QY3);   // 16-row aggregate
    if (lane < 16){
      waveC[tt & 1][w][col][0] = SA;
      waveC[tt & 1][w][col][1] = SY;
    }
    __syncthreads();
    // segment-exclusive prefix + tile aggregate (all threads, own col)
    float wpA = 1.0f, wpY = 0.0f, tAg = 1.0f, tYg = 0.0f;
    #pragma unroll
    for (int s = 0; s < 8; ++s){
      if (s == w){ wpA = tAg; wpY = tYg; }
      float cA = waveC[tt & 1][s][col][0];
      float cY = waveC[tt & 1][s][col][1];
      tYg = fmaf(cA, tYg, cY); tAg *= cA;
    }
    // final y, direct f32 stores
    float hpre = fmaf(wpA, hin, wpY);          // state entering wave's segment
    float v = fmaf(QpA, hpre, QpY);            // state entering thread's rows
    float* yp = y_out + (size_t)(mb + w * 16 + q * 4) * D_ + hcol;
    #pragma unroll
    for (int r = 0; r < 4; ++r){
      v = fmaf(av[r], v, bv[r]);
      yp[(size_t)r * D_] = v;
    }
    hin = fmaf(tAg, hin, tYg);
  };

  for (int t = 0; t < 32; t += 2){
    tile_step(Aa, Ab, xva, xvb, t);
    tile_step(Ab, Aa, xvb, xva, t + 1);
  }

  if (tid < 16)
    hlast[batch * D_ + h * 128 + cg * 16 + tid] = hin;
}

extern "C" void kernel_launch(void* const* d_in, const int* in_sizes, int n_in,
                              void* d_out, int out_size, void* d_ws, size_t ws_size,
                              hipStream_t stream) {
  const float* x    = (const float*)d_in[0];
  const float* ap   = (const float*)d_in[1];
  const float* w_in = (const float*)d_in[2];
  const float* w_a  = (const float*)d_in[3];
  float* y = (float*)d_out;                       // 16,777,216 floats
  float* hlast = y + (size_t)B_ * T_ * D_;        // + 4096 floats

  u16* wt = (u16*)d_ws;                           // 524,288 B

  k0_transpose<<<16, 256, 0, stream>>>(w_in, w_a, wt);
  k1_persist<<<256, 512, 0, stream>>>(x, ap, wt, y, hlast);
}